// Round 5
// baseline (339.087 us; speedup 1.0000x reference)
//
#include <hip/hip_runtime.h>

#define T_DIM 8192
#define D_DIM 256
#define N_DIM 64
#define LOG2E 1.44269504f

typedef __bf16 bf16x8 __attribute__((ext_vector_type(8)));
typedef __bf16 bf16x4 __attribute__((ext_vector_type(4)));
typedef float f32x16 __attribute__((ext_vector_type(16)));

__device__ __forceinline__ f32x16 zero16() {
  f32x16 v;
#pragma unroll
  for (int i = 0; i < 16; ++i) v[i] = 0.f;
  return v;
}

// ---------------------------------------------------------------------------
// Device-wide barrier: 8 sub-counters (64 blocks each) -> root(8) -> flag.
// Counters live in ws, zeroed per launch by hipMemsetAsync. Agent-scope
// RMW release-chain + relaxed spin + acquire fence (cross-XCD safe).
// ---------------------------------------------------------------------------
__device__ __forceinline__ void gbar(unsigned int* bar, int slot) {
  __syncthreads();
  if (threadIdx.x == 0) {
    __threadfence();  // release: push this CU's writes past L2
    const int bx = (int)blockIdx.x;
    unsigned int o = __hip_atomic_fetch_add(&bar[16 + slot * 8 + (bx & 7)], 1u,
                                            __ATOMIC_ACQ_REL,
                                            __HIP_MEMORY_SCOPE_AGENT);
    if (o == 63u) {
      unsigned int r = __hip_atomic_fetch_add(&bar[slot], 1u, __ATOMIC_ACQ_REL,
                                              __HIP_MEMORY_SCOPE_AGENT);
      if (r == 7u)
        __hip_atomic_store(&bar[8 + slot], 1u, __ATOMIC_RELEASE,
                           __HIP_MEMORY_SCOPE_AGENT);
    }
    while (__hip_atomic_load(&bar[8 + slot], __ATOMIC_RELAXED,
                             __HIP_MEMORY_SCOPE_AGENT) == 0u)
      __builtin_amdgcn_s_sleep(8);
    __threadfence();  // acquire: invalidate stale L1/L2 lines
  }
  __syncthreads();
}

// ---------------------------------------------------------------------------
// One persistent kernel, 512 blocks x 256 thr, 2 blocks/CU (64KB LDS union).
// Phases (device barriers between): A=dh, B=rowsum, C=scaleH, D=z, E=zred.
// Phase bodies are the R4-proven kernels, minimally remapped.
// ---------------------------------------------------------------------------
union SMem {
  struct {
    __bf16 Hs[2][8192];  // [dl][t] swizzled, 2 x 16 KB
    __bf16 Pt[2][8192];  // [j][t] swizzled,  2 x 16 KB
  } z;                   // 64 KB (phase D)
  __bf16 DHs[64 * 72];   // 9 KB (phase A)
  float red2[128][33];   // 16.9 KB (phase B)
  float rinvL[64];       // (phase C)
};

__global__ __launch_bounds__(256, 2) void k_fused(
    const float* __restrict__ H, const float* __restrict__ Dm,
    const float* __restrict__ l2p, float* __restrict__ Z,
    __bf16* __restrict__ DHf, float* __restrict__ lbe,
    float* __restrict__ rowsum, __bf16* __restrict__ Hbf_sw,
    float* __restrict__ Zp, unsigned int* __restrict__ bar) {
  __shared__ SMem smem;
  const int tid = threadIdx.x;
  const int bx = (int)blockIdx.x;
  const int lane = tid & 63;
  const int wave = tid >> 6;
  const int h = lane >> 5;
  const int l31 = lane & 31;

  // ========================= Phase A: DHf + lbe ===========================
  // blocks 0..127, t64 x n64 each. A-fragments via DIRECT column-coalesced
  // loads of H (no 67KB H^T staging): a[e] = H[kk*16+h*8+e][t0+m].
  if (bx < 128) {
    const int t0 = bx * 64;
    const int tt = wave & 1, nh = wave >> 1;
    const int m = tt * 32 + l31;
    const int n = nh * 32 + l31;
    f32x16 c = zero16();
    for (int kk = 0; kk < 16; ++kk) {
      float av[8];
#pragma unroll
      for (int e = 0; e < 8; ++e)
        av[e] = H[(size_t)(kk * 16 + h * 8 + e) * T_DIM + t0 + m];
      bf16x8 ahi, alo;
#pragma unroll
      for (int e = 0; e < 8; ++e) {
        __bf16 hi = (__bf16)av[e];
        ahi[e] = hi;
        alo[e] = (__bf16)(av[e] - (float)hi);
      }
      const float4* dp = (const float4*)(Dm + (size_t)n * 256 + kk * 16 + h * 8);
      float4 b0 = dp[0], b1 = dp[1];
      float bv[8] = {b0.x, b0.y, b0.z, b0.w, b1.x, b1.y, b1.z, b1.w};
      bf16x8 bhi, blo;
#pragma unroll
      for (int i = 0; i < 8; ++i) {
        __bf16 hi = (__bf16)bv[i];
        bhi[i] = hi;
        blo[i] = (__bf16)(bv[i] - (float)hi);
      }
      c = __builtin_amdgcn_mfma_f32_32x32x16_bf16(ahi, bhi, c, 0, 0, 0);
      c = __builtin_amdgcn_mfma_f32_32x32x16_bf16(ahi, blo, c, 0, 0, 0);
      c = __builtin_amdgcn_mfma_f32_32x32x16_bf16(alo, bhi, c, 0, 0, 0);
    }
#pragma unroll
    for (int r = 0; r < 16; ++r) {
      int row = tt * 32 + (r & 3) + 8 * (r >> 2) + 4 * h;
      smem.DHs[row * 72 + n] = (__bf16)c[r];
    }
    __syncthreads();
#pragma unroll
    for (int r = 0; r < 2; ++r) {
      int idx = r * 256 + tid;
      int g = idx >> 8, cc = (idx >> 5) & 7, l = idx & 31;
      bf16x8 w = *(const bf16x8*)&smem.DHs[(g * 32 + l) * 72 + cc * 8];
      *(bf16x8*)(DHf + (size_t)(bx * 2 + g) * 2048 + cc * 256 + l * 8) = w;
    }
    if (tid < 64) {
      float s = 0.f;
#pragma unroll
      for (int q = 0; q < 8; ++q) {
        bf16x8 w = *(const bf16x8*)&smem.DHs[tid * 72 + q * 8];
#pragma unroll
        for (int i = 0; i < 8; ++i) { float f = (float)w[i]; s += f * f; }
      }
      lbe[t0 + tid] = -0.5f * s * LOG2E;
      rowsum[t0 + tid] = 0.f;
    }
  }
  gbar(bar, 0);

  // ========================= Phase B: rowsum ==============================
  // 512 blocks: 64 t-tiles(128) x 8 j-splits(1024). 4 waves = 4 t32-groups,
  // 32 j-iters, b-prefetch. (R3-proven v3 remapped to 256 threads.)
  {
    const int t0 = (bx >> 3) * 128;
    const int jbase = (bx & 7) * 1024;
    const size_t Gt = (size_t)(t0 >> 5) + wave;
    bf16x8 aR[4];
#pragma unroll
    for (int kk = 0; kk < 4; ++kk)
      aR[kk] = *(const bf16x8*)(DHf + Gt * 2048 + kk * 512 + lane * 8);
    float racc[16];
#pragma unroll
    for (int r = 0; r < 16; ++r) racc[r] = 0.f;
    bf16x8 b[4];
    {
      const size_t Gj = (size_t)(jbase >> 5);
#pragma unroll
      for (int kk = 0; kk < 4; ++kk)
        b[kk] = *(const bf16x8*)(DHf + Gj * 2048 + kk * 512 + lane * 8);
    }
    for (int jit = 0; jit < 32; ++jit) {
      bf16x8 bn[4];
      if (jit < 31) {
        const size_t Gj = (size_t)(jbase >> 5) + jit + 1;
#pragma unroll
        for (int kk = 0; kk < 4; ++kk)
          bn[kk] = *(const bf16x8*)(DHf + Gj * 2048 + kk * 512 + lane * 8);
      }
      const float lbv = lbe[jbase + jit * 32 + l31];
      f32x16 s = zero16();
      s = __builtin_amdgcn_mfma_f32_32x32x16_bf16(aR[0], b[0], s, 0, 0, 0);
      s = __builtin_amdgcn_mfma_f32_32x32x16_bf16(aR[1], b[1], s, 0, 0, 0);
      s = __builtin_amdgcn_mfma_f32_32x32x16_bf16(aR[2], b[2], s, 0, 0, 0);
      s = __builtin_amdgcn_mfma_f32_32x32x16_bf16(aR[3], b[3], s, 0, 0, 0);
#pragma unroll
      for (int r = 0; r < 16; ++r)
        racc[r] += __builtin_amdgcn_exp2f(__builtin_fmaf(s[r], LOG2E, lbv));
      if (jit < 31) {
#pragma unroll
        for (int kk = 0; kk < 4; ++kk) b[kk] = bn[kk];
      }
    }
#pragma unroll
    for (int r = 0; r < 16; ++r) {
      int tl = wave * 32 + (r & 3) + 8 * (r >> 2) + 4 * h;
      smem.red2[tl][l31] = racc[r];
    }
    __syncthreads();
    if (tid < 128) {
      float s = 0.f;
#pragma unroll 8
      for (int c = 0; c < 32; ++c) s += smem.red2[tid][c];
      atomicAdd(&rowsum[t0 + tid], s);
    }
  }
  gbar(bar, 1);

  // ========================= Phase C: scaleH ==============================
  // 512 blocks = 256 work-units x 2 halves (itr pairs). Same math as R4.
  {
    const int u = bx >> 1;
    const int tblk = u >> 1, dh = u & 1;
    const int half = bx & 1;
    const int t0 = tblk * 64;
    if (tid < 64) smem.rinvL[tid] = 1.0f / rowsum[t0 + tid];
    __syncthreads();
#pragma unroll
    for (int ii = 0; ii < 2; ++ii) {
      int itr = half * 2 + ii;
      int idx = itr * 256 + tid;
      int dl = idx >> 3, tbp = idx & 7;
      int d = dh * 128 + dl;
      int swz = (d ^ (d >> 3)) & 7;
      int tloc = (tbp ^ swz) << 3;
      const float4* hp = (const float4*)(H + (size_t)d * T_DIM + t0 + tloc);
      float4 v0 = hp[0], v1 = hp[1];
      float4 r0 = *(const float4*)&smem.rinvL[tloc];
      float4 r1 = *(const float4*)&smem.rinvL[tloc + 4];
      bf16x8 w;
      w[0] = (__bf16)(v0.x * r0.x); w[1] = (__bf16)(v0.y * r0.y);
      w[2] = (__bf16)(v0.z * r0.z); w[3] = (__bf16)(v0.w * r0.w);
      w[4] = (__bf16)(v1.x * r1.x); w[5] = (__bf16)(v1.y * r1.y);
      w[6] = (__bf16)(v1.z * r1.z); w[7] = (__bf16)(v1.w * r1.w);
      *(bf16x8*)(Hbf_sw + (size_t)tblk * 16384 + (size_t)d * 64 + tbp * 8) = w;
    }
  }
  gbar(bar, 2);

  // ========================= Phase D: Z partial planes ====================
  // Byte-identical to R4's k_z (61.4us proven): 64 j-tiles x 2 dh x 4 ts,
  // double-buffered Hs/Pt, aR/aRn double-buffer, setprio Z-MFMA, plane
  // stores (no atomics).
  {
    const int ts = bx & 3;
    const int dh = (bx >> 2) & 1;
    const int j0 = (bx >> 3) * 128;
    const int s_tt = wave & 1, s_jg = wave >> 1;
    bf16x8 bS[2][4];
    float lbv[2];
#pragma unroll
    for (int q = 0; q < 2; ++q) {
      const size_t Gj = (j0 >> 5) + s_jg * 2 + q;
#pragma unroll
      for (int kk = 0; kk < 4; ++kk)
        bS[q][kk] = *(const bf16x8*)(DHf + Gj * 2048 + kk * 512 + lane * 8);
      lbv[q] = lbe[j0 + (s_jg * 2 + q) * 32 + l31];
    }
    f32x16 acc[2][2];
#pragma unroll
    for (int u = 0; u < 2; ++u)
#pragma unroll
      for (int v = 0; v < 2; ++v) acc[u][v] = zero16();

#define DMA_HS(buf_, it_)                                                       \
  {                                                                             \
    const __bf16* gsrc =                                                        \
        Hbf_sw + (size_t)(ts * 32 + (it_)) * 16384 + (size_t)dh * 8192;         \
    _Pragma("unroll") for (int r = 0; r < 4; ++r) {                             \
      int chunk = wave * 4 + r;                                                 \
      __builtin_amdgcn_global_load_lds(                                         \
          (const __attribute__((address_space(1))) unsigned int*)(gsrc +        \
              chunk * 512 + lane * 8),                                          \
          (__attribute__((address_space(3))) unsigned int*)(&smem.z.Hs[buf_][0] + \
              chunk * 512),                                                     \
          16, 0, 0);                                                            \
    }                                                                           \
  }

#define LOAD_AR(reg_, n_)                                                       \
  {                                                                             \
    const size_t Gt_ = (size_t)(ts * 64 + (n_)*2 + s_tt);                       \
    _Pragma("unroll") for (int kk = 0; kk < 4; ++kk)                            \
        (reg_)[kk] = *(const bf16x8*)(DHf + Gt_ * 2048 + kk * 512 + lane * 8);  \
  }

#define S_PHASE(p_, reg_)                                                       \
  {                                                                             \
    _Pragma("unroll") for (int q = 0; q < 2; ++q) {                             \
      f32x16 s = zero16();                                                      \
      _Pragma("unroll") for (int kk = 0; kk < 4; ++kk)                          \
          s = __builtin_amdgcn_mfma_f32_32x32x16_bf16((reg_)[kk], bS[q][kk], s, \
                                                      0, 0, 0);                 \
      const int jl = (s_jg * 2 + q) * 32 + l31;                                 \
      const int sj = (jl ^ (jl >> 3)) & 7;                                      \
      _Pragma("unroll") for (int g = 0; g < 4; ++g) {                           \
        const int tl = s_tt * 32 + g * 8 + 4 * h;                               \
        bf16x4 pv;                                                              \
        pv[0] = (__bf16)__builtin_amdgcn_exp2f(                                 \
            __builtin_fmaf(s[g * 4 + 0], LOG2E, lbv[q]));                       \
        pv[1] = (__bf16)__builtin_amdgcn_exp2f(                                 \
            __builtin_fmaf(s[g * 4 + 1], LOG2E, lbv[q]));                       \
        pv[2] = (__bf16)__builtin_amdgcn_exp2f(                                 \
            __builtin_fmaf(s[g * 4 + 2], LOG2E, lbv[q]));                       \
        pv[3] = (__bf16)__builtin_amdgcn_exp2f(                                 \
            __builtin_fmaf(s[g * 4 + 3], LOG2E, lbv[q]));                       \
        const int cchunk = tl >> 3;                                             \
        *(bf16x4*)&smem.z.Pt[p_][jl * 64 + ((cchunk ^ sj) << 3) + 4 * h] = pv;  \
      }                                                                         \
    }                                                                           \
  }

#define Z_PHASE(p_)                                                             \
  {                                                                             \
    __builtin_amdgcn_s_setprio(1);                                              \
    _Pragma("unroll") for (int kk = 0; kk < 4; ++kk) {                          \
      const int c = kk * 2 + h;                                                 \
      bf16x8 af[2], bw[2];                                                      \
      _Pragma("unroll") for (int u = 0; u < 2; ++u) {                           \
        int dl = (wave & 1) * 64 + u * 32 + l31;                                \
        af[u] = *(const bf16x8*)&smem.z                                         \
                     .Hs[p_][dl * 64 + ((c ^ ((dl ^ (dl >> 3)) & 7)) << 3)];    \
      }                                                                         \
      _Pragma("unroll") for (int v = 0; v < 2; ++v) {                           \
        int j = (wave >> 1) * 64 + v * 32 + l31;                                \
        bw[v] = *(const bf16x8*)&smem.z                                         \
                     .Pt[p_][j * 64 + ((c ^ ((j ^ (j >> 3)) & 7)) << 3)];       \
      }                                                                         \
      _Pragma("unroll") for (int u = 0; u < 2; ++u)                             \
          _Pragma("unroll") for (int v = 0; v < 2; ++v)                         \
              acc[u][v] = __builtin_amdgcn_mfma_f32_32x32x16_bf16(              \
                  af[u], bw[v], acc[u][v], 0, 0, 0);                            \
    }                                                                           \
    __builtin_amdgcn_s_setprio(0);                                              \
  }

    bf16x8 aR[4], aRn[4];
    LOAD_AR(aR, 0);
    DMA_HS(0, 0);
    S_PHASE(0, aR);
    LOAD_AR(aRn, 1);
    __syncthreads();

    for (int ii = 0; ii < 16; ++ii) {
      const int it0 = ii * 2;
      DMA_HS(1, it0 + 1);
      if (it0 < 30) LOAD_AR(aR, it0 + 2);
      S_PHASE(1, aRn);
      Z_PHASE(0);
      __syncthreads();
      if (it0 + 1 < 31) {
        DMA_HS(0, it0 + 2);
        S_PHASE(0, aR);
      }
      if (it0 + 1 < 30) LOAD_AR(aRn, it0 + 3);
      Z_PHASE(1);
      __syncthreads();
    }
#undef Z_PHASE
#undef S_PHASE
#undef LOAD_AR
#undef DMA_HS
    float* zp = Zp + (size_t)ts * (256 * (size_t)T_DIM);
#pragma unroll
    for (int u = 0; u < 2; ++u)
#pragma unroll
      for (int v = 0; v < 2; ++v)
#pragma unroll
        for (int r = 0; r < 16; ++r) {
          int d = dh * 128 + (wave & 1) * 64 + u * 32 + (r & 3) + 8 * (r >> 2) + 4 * h;
          int j = j0 + (wave >> 1) * 64 + v * 32 + l31;
          zp[(size_t)d * T_DIM + j] = acc[u][v][r];
        }
  }
  gbar(bar, 3);

  // ========================= Phase E: Z reduction =========================
  // 512K float4s over 131072 threads: 4 per thread, coalesced.
  {
    const float l2v = l2p[0];
    const float4* zp4 = (const float4*)Zp;
    float4* Z4 = (float4*)Z;
#pragma unroll
    for (int k = 0; k < 4; ++k) {
      int i = k * 131072 + bx * 256 + tid;
      float4 a = zp4[i];
#pragma unroll
      for (int s = 1; s < 4; ++s) {
        float4 b = zp4[(size_t)s * 524288 + i];
        a.x += b.x; a.y += b.y; a.z += b.z; a.w += b.w;
      }
      float4 o = {a.x * l2v, a.y * l2v, a.z * l2v, a.w * l2v};
      Z4[i] = o;
    }
  }
}

// ---------------------------------------------------------------------------
extern "C" void kernel_launch(void* const* d_in, const int* in_sizes, int n_in,
                              void* d_out, int out_size, void* d_ws,
                              size_t ws_size, hipStream_t stream) {
  (void)in_sizes; (void)n_in; (void)out_size; (void)ws_size;
  const float* H = (const float*)d_in[0];
  const float* Dm = (const float*)d_in[1];
  const float* l2 = (const float*)d_in[2];
  float* Z = (float*)d_out;
  char* ws = (char*)d_ws;
  __bf16* DHf = (__bf16*)ws;                         // 1,048,576 B
  float* lbe = (float*)(ws + 1048576);               // 32,768 B
  float* rowsum = (float*)(ws + 1081344);            // 32,768 B
  unsigned int* bar = (unsigned int*)(ws + 1114112); // 512 B
  __bf16* Hbf_sw = (__bf16*)(ws + 1114624);          // 4,194,304 B
  float* Zp = (float*)(ws + 5308928);                // 33,554,432 B

  hipMemsetAsync(bar, 0, 512, stream);
  k_fused<<<512, 256, 0, stream>>>(H, Dm, l2, Z, DHf, lbe, rowsum, Hbf_sw, Zp,
                                   bar);
}

// Round 6
// 151.135 us; speedup vs baseline: 2.2436x; 2.2436x over previous
//
#include <hip/hip_runtime.h>

#define T_DIM 8192
#define D_DIM 256
#define N_DIM 64
#define LOG2E 1.44269504f

typedef __bf16 bf16x8 __attribute__((ext_vector_type(8)));
typedef __bf16 bf16x4 __attribute__((ext_vector_type(4)));
typedef float f32x16 __attribute__((ext_vector_type(16)));

__device__ __forceinline__ f32x16 zero16() {
  f32x16 v;
#pragma unroll
  for (int i = 0; i < 16; ++i) v[i] = 0.f;
  return v;
}

// DHf: fragment-major. Row-group G=t>>5, chunk c=kk*2+h, lane l31:
// DHf[G*2048 + c*256 + l31*8 .. +7] = DH[n=c*8+e][t=G*32+l31].

// ---------------------------------------------------------------------------
// K1: blocks 0..127: DHf + lbe + rowsum=0 (R4-proven body).
//     blocks 128..383: Hbf = bf16(H) pre-swizzled to k_z's LDS image
//     (UNSCALED -- rowsum scaling moved to k_z's S-phase), independent work
//     riding in the same dispatch. grid 384 x 256.
// ---------------------------------------------------------------------------
__global__ __launch_bounds__(256) void k_dh(const float* __restrict__ H,
                                            const float* __restrict__ Dm,
                                            __bf16* __restrict__ DHf,
                                            float* __restrict__ lbe,
                                            float* __restrict__ rowsum,
                                            __bf16* __restrict__ Hbf) {
  __shared__ __bf16 HlThi[64 * 264];
  __shared__ __bf16 HlTlo[64 * 264];
  __shared__ __bf16 DHs[64 * 72];
  const int tid = threadIdx.x;
  const int bx = (int)blockIdx.x;
  const int lane = tid & 63;
  const int wave = tid >> 6;
  const int h = lane >> 5;
  const int l31 = lane & 31;

  if (bx >= 128) {
    // ---- cast blocks: Hbf (swizzled image), no rowsum dependency ----
    const int cbx = bx - 128;
    const int tblk = cbx >> 1, dh2 = cbx & 1;
    const int t0c = tblk * 64;
#pragma unroll
    for (int itr = 0; itr < 4; ++itr) {
      int idx = itr * 256 + tid;
      int dl = idx >> 3, tbp = idx & 7;
      int d = dh2 * 128 + dl;
      int swz = (d ^ (d >> 3)) & 7;
      int tloc = (tbp ^ swz) << 3;
      const float4* hp = (const float4*)(H + (size_t)d * T_DIM + t0c + tloc);
      float4 v0 = hp[0], v1 = hp[1];
      bf16x8 w;
      w[0] = (__bf16)v0.x; w[1] = (__bf16)v0.y;
      w[2] = (__bf16)v0.z; w[3] = (__bf16)v0.w;
      w[4] = (__bf16)v1.x; w[5] = (__bf16)v1.y;
      w[6] = (__bf16)v1.z; w[7] = (__bf16)v1.w;
      *(bf16x8*)(Hbf + (size_t)tblk * 16384 + (size_t)d * 64 + tbp * 8) = w;
    }
    return;
  }

  // ---- DH blocks (R4-proven) ----
  const int t0 = bx * 64;
  const float4* H4 = (const float4*)H;
#pragma unroll
  for (int r = 0; r < 16; ++r) {
    int idx = r * 256 + tid;
    int d = idx >> 4, tc = idx & 15;
    float4 v = H4[(size_t)d * (T_DIM / 4) + (t0 >> 2) + tc];
    float vv[4] = {v.x, v.y, v.z, v.w};
#pragma unroll
    for (int i = 0; i < 4; ++i) {
      __bf16 hi = (__bf16)vv[i];
      float lo = vv[i] - (float)hi;
      HlThi[(tc * 4 + i) * 264 + d] = hi;
      HlTlo[(tc * 4 + i) * 264 + d] = (__bf16)lo;
    }
  }
  __syncthreads();
  const int tt = wave & 1, nh = wave >> 1;
  const int m = tt * 32 + l31;
  const int n = nh * 32 + l31;
  f32x16 c = zero16();
  for (int kk = 0; kk < 16; ++kk) {
    bf16x8 ahi = *(const bf16x8*)&HlThi[m * 264 + kk * 16 + h * 8];
    bf16x8 alo = *(const bf16x8*)&HlTlo[m * 264 + kk * 16 + h * 8];
    const float4* dp = (const float4*)(Dm + (size_t)n * 256 + kk * 16 + h * 8);
    float4 b0 = dp[0], b1 = dp[1];
    float bv[8] = {b0.x, b0.y, b0.z, b0.w, b1.x, b1.y, b1.z, b1.w};
    bf16x8 bhi, blo;
#pragma unroll
    for (int i = 0; i < 8; ++i) {
      __bf16 hi = (__bf16)bv[i];
      bhi[i] = hi;
      blo[i] = (__bf16)(bv[i] - (float)hi);
    }
    c = __builtin_amdgcn_mfma_f32_32x32x16_bf16(ahi, bhi, c, 0, 0, 0);
    c = __builtin_amdgcn_mfma_f32_32x32x16_bf16(ahi, blo, c, 0, 0, 0);
    c = __builtin_amdgcn_mfma_f32_32x32x16_bf16(alo, bhi, c, 0, 0, 0);
  }
#pragma unroll
  for (int r = 0; r < 16; ++r) {
    int row = tt * 32 + (r & 3) + 8 * (r >> 2) + 4 * h;
    DHs[row * 72 + n] = (__bf16)c[r];
  }
  __syncthreads();
#pragma unroll
  for (int r = 0; r < 2; ++r) {
    int idx = r * 256 + tid;
    int g = idx >> 8, cc = (idx >> 5) & 7, l = idx & 31;
    bf16x8 w = *(const bf16x8*)&DHs[(g * 32 + l) * 72 + cc * 8];
    *(bf16x8*)(DHf + (size_t)(bx * 2 + g) * 2048 + cc * 256 + l * 8) = w;
  }
  if (tid < 64) {
    float s = 0.f;
#pragma unroll
    for (int q = 0; q < 8; ++q) {
      bf16x8 w = *(const bf16x8*)&DHs[tid * 72 + q * 8];
#pragma unroll
      for (int i = 0; i < 8; ++i) { float f = (float)w[i]; s += f * f; }
    }
    lbe[t0 + tid] = -0.5f * s * LOG2E;
    rowsum[t0 + tid] = 0.f;
  }
}

// ---------------------------------------------------------------------------
// K2 v3: rowsum[t] += sum_j exp(S+lb). grid 512 x 512 threads. (R3-proven)
// ---------------------------------------------------------------------------
__global__ __launch_bounds__(512, 4) void k_rowsum(const __bf16* __restrict__ DHf,
                                                   const float* __restrict__ lbe,
                                                   float* __restrict__ rowsum) {
  __shared__ float red2[256][33];
  const int tid = threadIdx.x;
  const int lane = tid & 63;
  const int wave = tid >> 6;
  const int h = lane >> 5;
  const int l31 = lane & 31;
  const int t0 = (int)(blockIdx.x >> 4) * 256;
  const int jbase = (int)(blockIdx.x & 15) * 512;
  const size_t Gt = (size_t)(t0 >> 5) + wave;
  bf16x8 aR[4];
#pragma unroll
  for (int kk = 0; kk < 4; ++kk)
    aR[kk] = *(const bf16x8*)(DHf + Gt * 2048 + kk * 512 + lane * 8);
  float racc[16];
#pragma unroll
  for (int r = 0; r < 16; ++r) racc[r] = 0.f;
  bf16x8 b[4];
  {
    const size_t Gj = (size_t)(jbase >> 5);
#pragma unroll
    for (int kk = 0; kk < 4; ++kk)
      b[kk] = *(const bf16x8*)(DHf + Gj * 2048 + kk * 512 + lane * 8);
  }
  for (int jit = 0; jit < 16; ++jit) {
    bf16x8 bn[4];
    if (jit < 15) {
      const size_t Gj = (size_t)(jbase >> 5) + jit + 1;
#pragma unroll
      for (int kk = 0; kk < 4; ++kk)
        bn[kk] = *(const bf16x8*)(DHf + Gj * 2048 + kk * 512 + lane * 8);
    }
    const float lbv = lbe[jbase + jit * 32 + l31];
    f32x16 s = zero16();
    s = __builtin_amdgcn_mfma_f32_32x32x16_bf16(aR[0], b[0], s, 0, 0, 0);
    s = __builtin_amdgcn_mfma_f32_32x32x16_bf16(aR[1], b[1], s, 0, 0, 0);
    s = __builtin_amdgcn_mfma_f32_32x32x16_bf16(aR[2], b[2], s, 0, 0, 0);
    s = __builtin_amdgcn_mfma_f32_32x32x16_bf16(aR[3], b[3], s, 0, 0, 0);
#pragma unroll
    for (int r = 0; r < 16; ++r)
      racc[r] += __builtin_amdgcn_exp2f(__builtin_fmaf(s[r], LOG2E, lbv));
    if (jit < 15) {
#pragma unroll
      for (int kk = 0; kk < 4; ++kk) b[kk] = bn[kk];
    }
  }
#pragma unroll
  for (int r = 0; r < 16; ++r) {
    int tl = wave * 32 + (r & 3) + 8 * (r >> 2) + 4 * h;
    red2[tl][l31] = racc[r];
  }
  __syncthreads();
  if (tid < 256) {
    float s = 0.f;
#pragma unroll 8
    for (int c = 0; c < 32; ++c) s += red2[tid][c];
    atomicAdd(&rowsum[t0 + tid], s);
  }
}

// ---------------------------------------------------------------------------
// K3: Zp[ts][d][j] = sum_{t in slice} (H[d][t]) * (E[t][j]*rinv[t]).
//     R4-proven pipeline; rinv applied in S-phase (4x float4 rowsum loads +
//     16 v_rcp + 16 mul per wave-iter, hides under existing stalls).
//     grid 512 = 64 j-tiles(128) x 2 d-halves x 4 t-splits; 2 blk/CU.
// ---------------------------------------------------------------------------
__global__ __launch_bounds__(256, 2) void k_z(const __bf16* __restrict__ Hbf,
                                              const __bf16* __restrict__ DHf,
                                              const float* __restrict__ lbe,
                                              const float* __restrict__ rowsum,
                                              float* __restrict__ Zp) {
  __shared__ __bf16 Hs[2][128 * 64];  // [dl][t] swizzled, 2 x 16 KB
  __shared__ __bf16 Pt[2][128 * 64];  // [j][t] swizzled,  2 x 16 KB
  const int tid = threadIdx.x;
  const int lane = tid & 63;
  const int wave = tid >> 6;
  const int h = lane >> 5;
  const int l31 = lane & 31;
  const int bx = blockIdx.x;
  const int ts = bx & 3;
  const int dh = (bx >> 2) & 1;
  const int j0 = (bx >> 3) * 128;
  const int s_tt = wave & 1, s_jg = wave >> 1;
  // resident S-phase B fragments + lbe
  bf16x8 bS[2][4];
  float lbv[2];
#pragma unroll
  for (int q = 0; q < 2; ++q) {
    const size_t Gj = (j0 >> 5) + s_jg * 2 + q;
#pragma unroll
    for (int kk = 0; kk < 4; ++kk)
      bS[q][kk] = *(const bf16x8*)(DHf + Gj * 2048 + kk * 512 + lane * 8);
    lbv[q] = lbe[j0 + (s_jg * 2 + q) * 32 + l31];
  }
  f32x16 acc[2][2];
#pragma unroll
  for (int u = 0; u < 2; ++u)
#pragma unroll
    for (int v = 0; v < 2; ++v) acc[u][v] = zero16();

  // DMA of H tile 'it_' into Hs[buf_]
#define DMA_HS(buf_, it_)                                                       \
  {                                                                             \
    const __bf16* gsrc =                                                        \
        Hbf + (size_t)(ts * 32 + (it_)) * 16384 + (size_t)dh * 8192;            \
    _Pragma("unroll") for (int r = 0; r < 4; ++r) {                             \
      int chunk = wave * 4 + r;                                                 \
      __builtin_amdgcn_global_load_lds(                                         \
          (const __attribute__((address_space(1))) unsigned int*)(gsrc +        \
              chunk * 512 + lane * 8),                                          \
          (__attribute__((address_space(3))) unsigned int*)(&Hs[buf_][0] +      \
              chunk * 512),                                                     \
          16, 0, 0);                                                            \
    }                                                                           \
  }

  // load A-fragments for t64-tile n_ into register array reg_
#define LOAD_AR(reg_, n_)                                                       \
  {                                                                             \
    const size_t Gt_ = (size_t)(ts * 64 + (n_)*2 + s_tt);                       \
    _Pragma("unroll") for (int kk = 0; kk < 4; ++kk)                            \
        (reg_)[kk] = *(const bf16x8*)(DHf + Gt_ * 2048 + kk * 512 + lane * 8);  \
  }

  // S-phase into Pt[p_] consuming fragment array reg_ (tile index n_ for
  // the rowsum base; rinv applied here, on the E side).
#define S_PHASE(p_, reg_, n_)                                                   \
  {                                                                             \
    const int rsb_ = ((ts * 32 + (n_)) << 6) + s_tt * 32 + 4 * h;               \
    float rv_[16];                                                              \
    _Pragma("unroll") for (int g = 0; g < 4; ++g) {                             \
      float4 rr = *(const float4*)&rowsum[rsb_ + g * 8];                        \
      rv_[g * 4 + 0] = __builtin_amdgcn_rcpf(rr.x);                             \
      rv_[g * 4 + 1] = __builtin_amdgcn_rcpf(rr.y);                             \
      rv_[g * 4 + 2] = __builtin_amdgcn_rcpf(rr.z);                             \
      rv_[g * 4 + 3] = __builtin_amdgcn_rcpf(rr.w);                             \
    }                                                                           \
    _Pragma("unroll") for (int q = 0; q < 2; ++q) {                             \
      f32x16 s = zero16();                                                      \
      _Pragma("unroll") for (int kk = 0; kk < 4; ++kk)                          \
          s = __builtin_amdgcn_mfma_f32_32x32x16_bf16((reg_)[kk], bS[q][kk], s, \
                                                      0, 0, 0);                 \
      const int jl = (s_jg * 2 + q) * 32 + l31;                                 \
      const int sj = (jl ^ (jl >> 3)) & 7;                                      \
      _Pragma("unroll") for (int g = 0; g < 4; ++g) {                           \
        const int tl = s_tt * 32 + g * 8 + 4 * h;                               \
        bf16x4 pv;                                                              \
        pv[0] = (__bf16)(__builtin_amdgcn_exp2f(                                \
            __builtin_fmaf(s[g * 4 + 0], LOG2E, lbv[q])) * rv_[g * 4 + 0]);     \
        pv[1] = (__bf16)(__builtin_amdgcn_exp2f(                                \
            __builtin_fmaf(s[g * 4 + 1], LOG2E, lbv[q])) * rv_[g * 4 + 1]);     \
        pv[2] = (__bf16)(__builtin_amdgcn_exp2f(                                \
            __builtin_fmaf(s[g * 4 + 2], LOG2E, lbv[q])) * rv_[g * 4 + 2]);     \
        pv[3] = (__bf16)(__builtin_amdgcn_exp2f(                                \
            __builtin_fmaf(s[g * 4 + 3], LOG2E, lbv[q])) * rv_[g * 4 + 3]);     \
        const int cchunk = tl >> 3;                                             \
        *(bf16x4*)&Pt[p_][jl * 64 + ((cchunk ^ sj) << 3) + 4 * h] = pv;         \
      }                                                                         \
    }                                                                           \
  }

  // Z-phase consuming buffers p_ (compile-time constant)
#define Z_PHASE(p_)                                                             \
  {                                                                             \
    __builtin_amdgcn_s_setprio(1);                                              \
    _Pragma("unroll") for (int kk = 0; kk < 4; ++kk) {                          \
      const int c = kk * 2 + h;                                                 \
      bf16x8 af[2], bw[2];                                                      \
      _Pragma("unroll") for (int u = 0; u < 2; ++u) {                           \
        int dl = (wave & 1) * 64 + u * 32 + l31;                                \
        af[u] =                                                                 \
            *(const bf16x8*)&Hs[p_][dl * 64 + ((c ^ ((dl ^ (dl >> 3)) & 7)) << 3)]; \
      }                                                                         \
      _Pragma("unroll") for (int v = 0; v < 2; ++v) {                           \
        int j = (wave >> 1) * 64 + v * 32 + l31;                                \
        bw[v] =                                                                 \
            *(const bf16x8*)&Pt[p_][j * 64 + ((c ^ ((j ^ (j >> 3)) & 7)) << 3)]; \
      }                                                                         \
      _Pragma("unroll") for (int u = 0; u < 2; ++u)                             \
          _Pragma("unroll") for (int v = 0; v < 2; ++v)                         \
              acc[u][v] = __builtin_amdgcn_mfma_f32_32x32x16_bf16(              \
                  af[u], bw[v], acc[u][v], 0, 0, 0);                            \
    }                                                                           \
    __builtin_amdgcn_s_setprio(0);                                              \
  }

  bf16x8 aR[4], aRn[4];
  LOAD_AR(aR, 0);
  DMA_HS(0, 0);
  S_PHASE(0, aR, 0);   // Pt[0] for tile 0
  LOAD_AR(aRn, 1);     // frags for tile 1
  __syncthreads();     // Hs[0] drained, Pt[0] visible

  for (int ii = 0; ii < 16; ++ii) {
    const int it0 = ii * 2;
    // ---- even iter: consume [0]; S builds [1] from aRn; load aR ----
    DMA_HS(1, it0 + 1);
    if (it0 < 30) LOAD_AR(aR, it0 + 2);
    S_PHASE(1, aRn, it0 + 1);
    Z_PHASE(0);
    __syncthreads();
    // ---- odd iter: consume [1]; S builds [0] from aR; load aRn ----
    if (it0 + 1 < 31) {
      DMA_HS(0, it0 + 2);
      S_PHASE(0, aR, it0 + 2);
    }
    if (it0 + 1 < 30) LOAD_AR(aRn, it0 + 3);
    Z_PHASE(1);
    __syncthreads();
  }
#undef Z_PHASE
#undef S_PHASE
#undef LOAD_AR
#undef DMA_HS
  // ---- epilogue: coalesced plane stores (no atomics) ----
  float* zp = Zp + (size_t)ts * (256 * (size_t)T_DIM);
#pragma unroll
  for (int u = 0; u < 2; ++u)
#pragma unroll
    for (int v = 0; v < 2; ++v)
#pragma unroll
      for (int r = 0; r < 16; ++r) {
        int d = dh * 128 + (wave & 1) * 64 + u * 32 + (r & 3) + 8 * (r >> 2) + 4 * h;
        int j = j0 + (wave >> 1) * 64 + v * 32 + l31;
        zp[(size_t)d * T_DIM + j] = acc[u][v][r];
      }
}

// ---------------------------------------------------------------------------
// K4: Z = l2 * sum_{ts=0..3} Zp[ts]. grid 2048 x 256, pure HBM-bound (~42MB).
// ---------------------------------------------------------------------------
__global__ __launch_bounds__(256) void k_zred(const float* __restrict__ Zp,
                                              const float* __restrict__ l2p,
                                              float* __restrict__ Z) {
  const int i = blockIdx.x * 256 + threadIdx.x;  // 524288 float4s total
  const float l2v = l2p[0];
  const float4* zp4 = (const float4*)Zp;
  float4 a = zp4[i];
#pragma unroll
  for (int s = 1; s < 4; ++s) {
    float4 b = zp4[(size_t)s * 524288 + i];
    a.x += b.x; a.y += b.y; a.z += b.z; a.w += b.w;
  }
  float4 o = {a.x * l2v, a.y * l2v, a.z * l2v, a.w * l2v};
  ((float4*)Z)[i] = o;
}

// ---------------------------------------------------------------------------
extern "C" void kernel_launch(void* const* d_in, const int* in_sizes, int n_in,
                              void* d_out, int out_size, void* d_ws,
                              size_t ws_size, hipStream_t stream) {
  (void)in_sizes; (void)n_in; (void)out_size; (void)ws_size;
  const float* H = (const float*)d_in[0];
  const float* Dm = (const float*)d_in[1];
  const float* l2 = (const float*)d_in[2];
  float* Z = (float*)d_out;
  char* ws = (char*)d_ws;
  __bf16* DHf = (__bf16*)ws;                        // 1,048,576 B
  float* lbe = (float*)(ws + 1048576);              // 32,768 B
  float* rowsum = (float*)(ws + 1048576 + 32768);   // 32,768 B
  __bf16* Hbf = (__bf16*)(ws + 1114112);            // 4,194,304 B
  float* Zp = (float*)(ws + 5308416);               // 33,554,432 B (4 planes)

  k_dh<<<384, 256, 0, stream>>>(H, Dm, DHf, lbe, rowsum, Hbf);
  k_rowsum<<<512, 512, 0, stream>>>(DHf, lbe, rowsum);
  k_z<<<512, 256, 0, stream>>>(Hbf, DHf, lbe, rowsum, Zp);
  k_zred<<<2048, 256, 0, stream>>>(Zp, l2, Z);
}